// Round 1
// baseline (573.473 us; speedup 1.0000x reference)
//
#include <hip/hip_runtime.h>
#include <stdint.h>
#include <math.h>

#define SEQ 4096
#define DM  1024
#define N3  3072
#define NH  16
#define DH  64

typedef short bf16x8 __attribute__((ext_vector_type(8)));
typedef float f32x4  __attribute__((ext_vector_type(4)));

__device__ __forceinline__ short f2bf(float f) {
    union { float f; uint32_t u; } x; x.f = f;
    uint32_t r = (x.u + 0x7fffu + ((x.u >> 16) & 1u)) >> 16;
    return (short)r;
}

// kqv[S][3072] (bf16) = x[S][1024] (fp32) @ w[1024][3072] (fp32)
// Column order: [0,1024)=K, [1024,2048)=Q, [2048,3072)=V  (reference splits k,q,v)
__global__ __launch_bounds__(256) void qkv_gemm(const float* __restrict__ x,
                                                const float* __restrict__ w,
                                                short* __restrict__ kqv) {
    __shared__ short As[64 * 32];   // A tile [m][k]
    __shared__ short Bst[64 * 32];  // B tile transposed [n][k]
    const int col0 = blockIdx.x * 64;
    const int row0 = blockIdx.y * 64;
    const int tid  = threadIdx.x;
    const int wave = tid >> 6, lane = tid & 63;
    const int lmod = lane & 15, ldiv = lane >> 4;
    const int wr = (wave >> 1) * 32, wc = (wave & 1) * 32;

    f32x4 acc[2][2] = {};

    for (int k0 = 0; k0 < DM; k0 += 32) {
        __syncthreads();
        {   // stage A 64x32: thread -> row tid/4, 8-elem chunk (tid%4)*8
            const int m = tid >> 2, kc = (tid & 3) * 8;
            const float4* src = (const float4*)(x + (size_t)(row0 + m) * DM + k0 + kc);
            float4 a0 = src[0], a1 = src[1];
            bf16x8 pk;
            pk[0]=f2bf(a0.x); pk[1]=f2bf(a0.y); pk[2]=f2bf(a0.z); pk[3]=f2bf(a0.w);
            pk[4]=f2bf(a1.x); pk[5]=f2bf(a1.y); pk[6]=f2bf(a1.z); pk[7]=f2bf(a1.w);
            *(bf16x8*)(&As[m * 32 + kc]) = pk;
        }
        {   // stage B 32x64 transposed: thread -> k row tid/8, 8-col chunk (tid%8)*8
            const int k = tid >> 3, nc = (tid & 7) * 8;
            const float4* src = (const float4*)(w + (size_t)(k0 + k) * N3 + col0 + nc);
            float4 b0 = src[0], b1 = src[1];
            float bv[8] = {b0.x, b0.y, b0.z, b0.w, b1.x, b1.y, b1.z, b1.w};
            #pragma unroll
            for (int e = 0; e < 8; ++e) Bst[(nc + e) * 32 + k] = f2bf(bv[e]);
        }
        __syncthreads();

        bf16x8 af[2], bfr[2];
        #pragma unroll
        for (int i = 0; i < 2; ++i)
            af[i] = *(const bf16x8*)(&As[(wr + i * 16 + lmod) * 32 + ldiv * 8]);
        #pragma unroll
        for (int j = 0; j < 2; ++j)
            bfr[j] = *(const bf16x8*)(&Bst[(wc + j * 16 + lmod) * 32 + ldiv * 8]);
        #pragma unroll
        for (int i = 0; i < 2; ++i)
            #pragma unroll
            for (int j = 0; j < 2; ++j)
                acc[i][j] = __builtin_amdgcn_mfma_f32_16x16x32_bf16(af[i], bfr[j], acc[i][j], 0, 0, 0);
    }

    // C/D layout: col = lane&15, row = (lane>>4)*4 + reg
    #pragma unroll
    for (int i = 0; i < 2; ++i)
        #pragma unroll
        for (int j = 0; j < 2; ++j)
            #pragma unroll
            for (int r = 0; r < 4; ++r)
                kqv[(size_t)(row0 + wr + i * 16 + ldiv * 4 + r) * N3
                    + col0 + wc + j * 16 + lmod] = f2bf(acc[i][j][r]);
}

// Flash attention with ALiBi + causal mask. One block per (q-tile of 64 rows, head).
// Each of 4 waves owns 16 q-rows.
__global__ __launch_bounds__(256) void attn(const short* __restrict__ kqv,
                                            float* __restrict__ out) {
    __shared__ short Ks[64 * 64];        // K tile [j][d]
    __shared__ short Vt[64 * 64];        // V tile transposed [d][j]
    __shared__ short Ps[4 * 16 * 64];    // per-wave P [row][j]

    const int qt = blockIdx.x, h = blockIdx.y;
    const int tid = threadIdx.x, wave = tid >> 6, lane = tid & 63;
    const int lmod = lane & 15, ldiv = lane >> 4;
    const float slope = exp2f(-0.5f * (float)(h + 1));  // (256^(1/16))^-(h+1) = 2^(-(h+1)/2)
    const float scale = 1.0f / 32.0f;                    // 1/sqrt(1024)

    // Q fragments (resident across the whole K loop); rows contiguous in d in global.
    bf16x8 qf[2];
    {
        const int row = qt * 64 + wave * 16 + lmod;
        const short* qp = kqv + (size_t)row * N3 + DM + h * DH;
        qf[0] = *(const bf16x8*)(qp + 0 * 32 + ldiv * 8);
        qf[1] = *(const bf16x8*)(qp + 1 * 32 + ldiv * 8);
    }

    float m_r[4], l_r[4];
    f32x4 O[4] = {};
    #pragma unroll
    for (int r = 0; r < 4; ++r) { m_r[r] = -INFINITY; l_r[r] = 0.f; }

    for (int kt = 0; kt <= qt; ++kt) {
        __syncthreads();
        // stage K tile (rows contiguous): 512 16B-chunks over 256 threads
        #pragma unroll
        for (int cc = 0; cc < 2; ++cc) {
            const int c = tid + cc * 256;
            const int row = c >> 3, ch = c & 7;
            const uint4 v = *(const uint4*)(kqv + (size_t)(kt * 64 + row) * N3 + h * DH + ch * 8);
            *(uint4*)(&Ks[c * 8]) = v;
        }
        // stage V transposed: thread -> v-row tid/4, 16-d chunk (tid%4)*16
        {
            const int j = tid >> 2, dc = (tid & 3) * 16;
            const short* vp = kqv + (size_t)(kt * 64 + j) * N3 + 2 * DM + h * DH + dc;
            #pragma unroll
            for (int e = 0; e < 16; ++e) Vt[(dc + e) * 64 + j] = vp[e];
        }
        __syncthreads();

        // S = Q K^T  (M=16 q-rows, N=64 j, K=64 d)
        f32x4 s[4] = {};
        #pragma unroll
        for (int nt = 0; nt < 4; ++nt) {
            #pragma unroll
            for (int ks = 0; ks < 2; ++ks) {
                bf16x8 bfr = *(const bf16x8*)(&Ks[(nt * 16 + lmod) * 64 + ks * 32 + ldiv * 8]);
                s[nt] = __builtin_amdgcn_mfma_f32_16x16x32_bf16(qf[ks], bfr, s[nt], 0, 0, 0);
            }
        }

        // scale + ALiBi bias + causal mask (C layout: row=(ldiv*4+r), col=nt*16+lmod)
        const int i0 = qt * 64 + wave * 16 + ldiv * 4;
        const int j0 = kt * 64 + lmod;
        float sv[4][4], rowmax[4];
        #pragma unroll
        for (int r = 0; r < 4; ++r) rowmax[r] = -INFINITY;
        #pragma unroll
        for (int nt = 0; nt < 4; ++nt) {
            #pragma unroll
            for (int r = 0; r < 4; ++r) {
                const int i = i0 + r, j = j0 + nt * 16;
                float v = s[nt][r] * scale + slope * (float)(j - i);
                if (j > i) v = -INFINITY;
                sv[nt][r] = v;
                rowmax[r] = fmaxf(rowmax[r], v);
            }
        }
        #pragma unroll
        for (int r = 0; r < 4; ++r) {
            float v = rowmax[r];
            v = fmaxf(v, __shfl_xor(v, 1, 16));
            v = fmaxf(v, __shfl_xor(v, 2, 16));
            v = fmaxf(v, __shfl_xor(v, 4, 16));
            v = fmaxf(v, __shfl_xor(v, 8, 16));
            rowmax[r] = v;
        }
        float alpha[4], rowsum[4];
        #pragma unroll
        for (int r = 0; r < 4; ++r) {
            const float mn = fmaxf(m_r[r], rowmax[r]);
            alpha[r] = expf(m_r[r] - mn);   // exp(-inf)=0 handles first tile
            m_r[r] = mn;
            rowsum[r] = 0.f;
        }
        #pragma unroll
        for (int nt = 0; nt < 4; ++nt) {
            #pragma unroll
            for (int r = 0; r < 4; ++r) {
                const float p = expf(sv[nt][r] - m_r[r]);  // masked: exp(-inf)=0
                sv[nt][r] = p;
                rowsum[r] += p;
            }
        }
        #pragma unroll
        for (int r = 0; r < 4; ++r) {
            float v = rowsum[r];
            v += __shfl_xor(v, 1, 16);
            v += __shfl_xor(v, 2, 16);
            v += __shfl_xor(v, 4, 16);
            v += __shfl_xor(v, 8, 16);
            l_r[r] = l_r[r] * alpha[r] + v;
        }
        // rescale O accumulator
        #pragma unroll
        for (int nt = 0; nt < 4; ++nt)
            #pragma unroll
            for (int r = 0; r < 4; ++r) O[nt][r] *= alpha[r];

        // P: C-layout regs -> LDS -> A-layout frags (per-wave region)
        short* pw = &Ps[wave * 1024];
        #pragma unroll
        for (int nt = 0; nt < 4; ++nt)
            #pragma unroll
            for (int r = 0; r < 4; ++r)
                pw[(ldiv * 4 + r) * 64 + nt * 16 + lmod] = f2bf(sv[nt][r]);
        __syncthreads();

        // O += P V  (M=16 q-rows, N=64 d, K=64 j)
        #pragma unroll
        for (int nt = 0; nt < 4; ++nt) {
            #pragma unroll
            for (int ks = 0; ks < 2; ++ks) {
                bf16x8 af  = *(const bf16x8*)(&pw[lmod * 64 + ks * 32 + ldiv * 8]);
                bf16x8 bfr = *(const bf16x8*)(&Vt[(nt * 16 + lmod) * 64 + ks * 32 + ldiv * 8]);
                O[nt] = __builtin_amdgcn_mfma_f32_16x16x32_bf16(af, bfr, O[nt], 0, 0, 0);
            }
        }
    }

    // epilogue: out[i][h*64 + d] = O / l
    const int i0 = qt * 64 + wave * 16 + ldiv * 4;
    #pragma unroll
    for (int nt = 0; nt < 4; ++nt)
        #pragma unroll
        for (int r = 0; r < 4; ++r)
            out[(size_t)(i0 + r) * DM + h * DH + nt * 16 + lmod] = O[nt][r] / l_r[r];
}

extern "C" void kernel_launch(void* const* d_in, const int* in_sizes, int n_in,
                              void* d_out, int out_size, void* d_ws, size_t ws_size,
                              hipStream_t stream) {
    const float* x = (const float*)d_in[0];   // [1, 4096, 1024] fp32
    const float* w = (const float*)d_in[1];   // [1024, 3072] fp32
    float* out = (float*)d_out;               // [1, 4096, 1024] fp32
    short* kqv = (short*)d_ws;                // bf16 [4096][3072] = 25.2 MB scratch

    qkv_gemm<<<dim3(N3 / 64, SEQ / 64), 256, 0, stream>>>(x, w, kqv);
    attn<<<dim3(SEQ / 64, NH), 256, 0, stream>>>(kqv, out);
}

// Round 2
// 241.811 us; speedup vs baseline: 2.3716x; 2.3716x over previous
//
#include <hip/hip_runtime.h>
#include <stdint.h>
#include <math.h>

#define SEQ 4096
#define DM  1024
#define NH  16
#define DH  64
#define KPAD 72
#define LOG2E 1.44269504088896341f

typedef short bf16x8 __attribute__((ext_vector_type(8)));
typedef short bf16x4 __attribute__((ext_vector_type(4)));
typedef float f32x4  __attribute__((ext_vector_type(4)));

typedef const __attribute__((address_space(1))) short* gptr_t;
typedef __attribute__((address_space(3))) short* lptr_t;

__device__ __forceinline__ short f2bf(float f) {
    union { float f; uint32_t u; } x; x.f = f;
    uint32_t r = (x.u + 0x7fffu + ((x.u >> 16) & 1u)) >> 16;
    return (short)r;
}

__device__ __forceinline__ void load_lds16(const short* g, const short* l) {
    __builtin_amdgcn_global_load_lds((gptr_t)(uintptr_t)g,
                                     (lptr_t)(uint32_t)(uintptr_t)l, 16, 0, 0);
}

// ---- prep: x fp32 -> bf16 ----
__global__ __launch_bounds__(256) void cvt_x(const float* __restrict__ x,
                                             short* __restrict__ xb) {
    const int i = (blockIdx.x * 256 + threadIdx.x) * 8;
    float4 a = ((const float4*)(x + i))[0];
    float4 b = ((const float4*)(x + i))[1];
    bf16x8 p;
    p[0]=f2bf(a.x); p[1]=f2bf(a.y); p[2]=f2bf(a.z); p[3]=f2bf(a.w);
    p[4]=f2bf(b.x); p[5]=f2bf(b.y); p[6]=f2bf(b.z); p[7]=f2bf(b.w);
    *(bf16x8*)(xb + i) = p;
}

// ---- prep: w [1024][3072] fp32 -> wtb [3072][1024] bf16 (transposed),
//      Q columns (rows 1024..2047 of wtb) pre-scaled by log2e/32 ----
__global__ __launch_bounds__(256) void cvt_wt(const float* __restrict__ w,
                                              short* __restrict__ wtb) {
    __shared__ float T[64][69];
    const int n0 = blockIdx.x * 64, k0 = blockIdx.y * 64;
    const int t = threadIdx.x;
    {
        const int kr = t >> 4, nc = (t & 15) * 4;
        #pragma unroll
        for (int i = 0; i < 4; ++i) {
            float4 v = *(const float4*)(w + (size_t)(k0 + kr + i * 16) * 3072 + n0 + nc);
            T[kr + i * 16][nc + 0] = v.x; T[kr + i * 16][nc + 1] = v.y;
            T[kr + i * 16][nc + 2] = v.z; T[kr + i * 16][nc + 3] = v.w;
        }
    }
    __syncthreads();
    const int nr = t >> 4, kc = (t & 15) * 4;
    #pragma unroll
    for (int i = 0; i < 4; ++i) {
        const int n = n0 + nr + i * 16;
        const float sc = (n >= 1024 && n < 2048) ? (LOG2E / 32.0f) : 1.0f;
        short4 o;
        o.x = f2bf(T[kc + 0][nr + i * 16] * sc);
        o.y = f2bf(T[kc + 1][nr + i * 16] * sc);
        o.z = f2bf(T[kc + 2][nr + i * 16] * sc);
        o.w = f2bf(T[kc + 3][nr + i * 16] * sc);
        *(short4*)(wtb + (size_t)n * 1024 + k0 + kc) = o;
    }
}

// ---- QKV GEMM (m97 structure): 128x128 tile, BK=64, global_load_lds ----
// A = xb[4096][1024], B^T = wtb[3072][1024]. Output: K,Q -> kq[4096][2048];
// V -> vt[16][64][4096] (transposed per head, for conflict-free attn staging).
__global__ __launch_bounds__(256) void qkv_gemm(const short* __restrict__ xb,
                                                const short* __restrict__ wtb,
                                                short* __restrict__ kq,
                                                short* __restrict__ vt) {
    __shared__ short As[128 * 64];
    __shared__ short Bs[128 * 64];
    const int col0 = blockIdx.x * 128, row0 = blockIdx.y * 128;
    const int tid = threadIdx.x, w = tid >> 6, lane = tid & 63;
    const int lmod = lane & 15, ldiv = lane >> 4;
    const int wr = (w >> 1) * 64, wc = (w & 1) * 64;

    f32x4 acc[4][4] = {};
    const short* Ag = xb  + (size_t)row0 * DM;
    const short* Bg = wtb + (size_t)col0 * DM;

    for (int k0 = 0; k0 < DM; k0 += 64) {
        __syncthreads();
        #pragma unroll
        for (int t = 0; t < 4; ++t) {
            const int o = (w * 4 + t) * 1024 + lane * 16;   // byte off in 16KB tile
            const int r = o >> 7, cs = (o & 127) >> 1;       // row, short-in-row
            load_lds16(Ag + (size_t)r * DM + k0 + cs, As + (w * 4 + t) * 512);
            load_lds16(Bg + (size_t)r * DM + k0 + cs, Bs + (w * 4 + t) * 512);
        }
        __syncthreads();
        #pragma unroll
        for (int ks = 0; ks < 2; ++ks) {
            bf16x8 af[4], bf[4];
            #pragma unroll
            for (int i = 0; i < 4; ++i)
                af[i] = *(const bf16x8*)(As + (wr + i * 16 + lmod) * 64 + ks * 32 + ldiv * 8);
            #pragma unroll
            for (int j = 0; j < 4; ++j)
                bf[j] = *(const bf16x8*)(Bs + (wc + j * 16 + lmod) * 64 + ks * 32 + ldiv * 8);
            #pragma unroll
            for (int i = 0; i < 4; ++i)
                #pragma unroll
                for (int j = 0; j < 4; ++j)
                    acc[i][j] = __builtin_amdgcn_mfma_f32_16x16x32_bf16(af[i], bf[j], acc[i][j], 0, 0, 0);
        }
    }

    if (col0 < 2048) {  // K/Q block -> kq[row][col]
        #pragma unroll
        for (int i = 0; i < 4; ++i)
            #pragma unroll
            for (int j = 0; j < 4; ++j)
                #pragma unroll
                for (int r = 0; r < 4; ++r)
                    kq[(size_t)(row0 + wr + i * 16 + ldiv * 4 + r) * 2048
                       + col0 + wc + j * 16 + lmod] = f2bf(acc[i][j][r]);
    } else {            // V block -> vt[h][d][seq] (4 consecutive seq per lane: 8B store)
        #pragma unroll
        for (int i = 0; i < 4; ++i) {
            const int ig = row0 + wr + i * 16 + ldiv * 4;
            #pragma unroll
            for (int j = 0; j < 4; ++j) {
                const int cg = col0 + wc + j * 16 + lmod - 2048;
                const int h = cg >> 6, d = cg & 63;
                bf16x4 p;
                p[0]=f2bf(acc[i][j][0]); p[1]=f2bf(acc[i][j][1]);
                p[2]=f2bf(acc[i][j][2]); p[3]=f2bf(acc[i][j][3]);
                *(bf16x4*)(vt + (size_t)(h * 64 + d) * SEQ + ig) = p;
            }
        }
    }
}

// ---- flash attention, ALiBi + causal, fixed-max (M=0) exp2-domain softmax ----
// Q pre-scaled by log2e/32 (folded into wtb). 1D grid, longest qt first.
__global__ __launch_bounds__(256, 4) void attn(const short* __restrict__ kq,
                                               const short* __restrict__ vt,
                                               float* __restrict__ out) {
    __shared__ short Ks[64 * KPAD];
    __shared__ short Vs[64 * KPAD];
    __shared__ short Ps[4 * 16 * KPAD];

    const int b = blockIdx.x;
    const int qt = 63 - (b >> 4);
    const int h  = b & 15;
    const int tid = threadIdx.x, w = tid >> 6, lane = tid & 63;
    const int lmod = lane & 15, ldiv = lane >> 4;
    const float slope2 = exp2f(-0.5f * (float)(h + 1)) * LOG2E;  // slope * log2(e)

    bf16x8 qf[2];
    {
        const int row = qt * 64 + w * 16 + lmod;
        const short* qp = kq + (size_t)row * 2048 + 1024 + h * 64;
        qf[0] = *(const bf16x8*)(qp + ldiv * 8);
        qf[1] = *(const bf16x8*)(qp + 32 + ldiv * 8);
    }

    f32x4 O[4] = {};
    float lsum[4] = {0.f, 0.f, 0.f, 0.f};
    short* pw = Ps + w * 16 * KPAD;

    auto body = [&](int kt, bool diag) {
        __syncthreads();
        #pragma unroll
        for (int cc = 0; cc < 2; ++cc) {
            const int c = tid + cc * 256;
            const int r = c >> 3, ch = c & 7;
            *(uint4*)(Ks + r * KPAD + ch * 8) =
                *(const uint4*)(kq + (size_t)(kt * 64 + r) * 2048 + h * 64 + ch * 8);
            *(uint4*)(Vs + r * KPAD + ch * 8) =
                *(const uint4*)(vt + (size_t)(h * 64 + r) * SEQ + kt * 64 + ch * 8);
        }
        __syncthreads();

        // S = Q K^T  (log2-domain, already scaled)
        f32x4 s[4] = {};
        #pragma unroll
        for (int nt = 0; nt < 4; ++nt)
            #pragma unroll
            for (int ks = 0; ks < 2; ++ks) {
                bf16x8 kf = *(const bf16x8*)(Ks + (nt * 16 + lmod) * KPAD + ks * 32 + ldiv * 8);
                s[nt] = __builtin_amdgcn_mfma_f32_16x16x32_bf16(qf[ks], kf, s[nt], 0, 0, 0);
            }

        // bias + exp2 (fixed max), accumulate per-lane row sums, write P (bf16)
        const int i0 = w * 16 + ldiv * 4;        // within-tile row
        const int dj0 = (kt - qt) * 64 - i0 + lmod;  // j - i for nt=0, r=0
        #pragma unroll
        for (int nt = 0; nt < 4; ++nt) {
            #pragma unroll
            for (int r = 0; r < 4; ++r) {
                const int dj = dj0 + nt * 16 - r;
                float v = s[nt][r] + slope2 * (float)dj;
                if (diag && dj > 0) v = -1e30f;
                const float p = __builtin_amdgcn_exp2f(v);
                lsum[r] += p;
                pw[(ldiv * 4 + r) * KPAD + nt * 16 + lmod] = f2bf(p);
            }
        }
        // P is per-wave: same-wave LDS RAW needs no barrier (lgkmcnt handles it)
        bf16x8 pa[2];
        pa[0] = *(const bf16x8*)(pw + lmod * KPAD + ldiv * 8);
        pa[1] = *(const bf16x8*)(pw + lmod * KPAD + 32 + ldiv * 8);
        #pragma unroll
        for (int nt = 0; nt < 4; ++nt)
            #pragma unroll
            for (int ks = 0; ks < 2; ++ks) {
                bf16x8 vf = *(const bf16x8*)(Vs + (nt * 16 + lmod) * KPAD + ks * 32 + ldiv * 8);
                O[nt] = __builtin_amdgcn_mfma_f32_16x16x32_bf16(pa[ks], vf, O[nt], 0, 0, 0);
            }
    };

    for (int kt = 0; kt < qt; ++kt) body(kt, false);
    body(qt, true);

    // reduce row sums across the 16-lane groups, then write out
    #pragma unroll
    for (int r = 0; r < 4; ++r) {
        float v = lsum[r];
        v += __shfl_xor(v, 1, 16);
        v += __shfl_xor(v, 2, 16);
        v += __shfl_xor(v, 4, 16);
        v += __shfl_xor(v, 8, 16);
        lsum[r] = 1.0f / v;
    }
    const int i0 = qt * 64 + w * 16 + ldiv * 4;
    #pragma unroll
    for (int nt = 0; nt < 4; ++nt)
        #pragma unroll
        for (int r = 0; r < 4; ++r)
            out[(size_t)(i0 + r) * DM + h * 64 + nt * 16 + lmod] = O[nt][r] * lsum[r];
}

extern "C" void kernel_launch(void* const* d_in, const int* in_sizes, int n_in,
                              void* d_out, int out_size, void* d_ws, size_t ws_size,
                              hipStream_t stream) {
    const float* x = (const float*)d_in[0];   // [1,4096,1024] fp32
    const float* w = (const float*)d_in[1];   // [1024,3072] fp32
    float* out = (float*)d_out;

    char* ws = (char*)d_ws;
    short* xb  = (short*)(ws);                        //  8 MB: x bf16
    short* wtb = (short*)(ws + ((size_t)8  << 20));   //  6 MB: w^T bf16 (Q-scaled)
    short* kq  = (short*)(ws + ((size_t)14 << 20));   // 16 MB: K|Q [4096][2048]
    short* vt  = (short*)(ws + ((size_t)30 << 20));   //  8 MB: V^T [16][64][4096]

    cvt_x  <<<SEQ * DM / (256 * 8), 256, 0, stream>>>(x, xb);
    cvt_wt <<<dim3(3072 / 64, 1024 / 64), 256, 0, stream>>>(w, wtb);
    qkv_gemm<<<dim3(3072 / 128, SEQ / 128), 256, 0, stream>>>(xb, wtb, kq, vt);
    attn   <<<64 * NH, 256, 0, stream>>>(kq, vt, out);
}

// Round 3
// 214.793 us; speedup vs baseline: 2.6699x; 1.1258x over previous
//
#include <hip/hip_runtime.h>
#include <stdint.h>
#include <math.h>

#define SEQ 4096
#define DM  1024
#define NH  16
#define DH  64
#define KPAD 72
#define PPAD 80
#define LOG2E 1.44269504088896341f

typedef short bf16x8 __attribute__((ext_vector_type(8)));
typedef short bf16x4 __attribute__((ext_vector_type(4)));
typedef float f32x4  __attribute__((ext_vector_type(4)));

typedef const __attribute__((address_space(1))) short* gptr_t;
typedef __attribute__((address_space(3))) short* lptr_t;

__device__ __forceinline__ short f2bf(float f) {
    union { float f; uint32_t u; } x; x.f = f;
    uint32_t r = (x.u + 0x7fffu + ((x.u >> 16) & 1u)) >> 16;
    return (short)r;
}

__device__ __forceinline__ void load_lds16(const short* g, const short* l) {
    __builtin_amdgcn_global_load_lds((gptr_t)(uintptr_t)g,
                                     (lptr_t)(uint32_t)(uintptr_t)l, 16, 0, 0);
}

// ---- prep: x fp32 -> bf16 ----
__global__ __launch_bounds__(256) void cvt_x(const float* __restrict__ x,
                                             short* __restrict__ xb) {
    const int i = (blockIdx.x * 256 + threadIdx.x) * 8;
    float4 a = ((const float4*)(x + i))[0];
    float4 b = ((const float4*)(x + i))[1];
    bf16x8 p;
    p[0]=f2bf(a.x); p[1]=f2bf(a.y); p[2]=f2bf(a.z); p[3]=f2bf(a.w);
    p[4]=f2bf(b.x); p[5]=f2bf(b.y); p[6]=f2bf(b.z); p[7]=f2bf(b.w);
    *(bf16x8*)(xb + i) = p;
}

// ---- prep: w [1024][3072] fp32 -> wtb [3072][1024] bf16 (transposed),
//      Q columns (rows 1024..2047 of wtb) pre-scaled by log2e/32 ----
__global__ __launch_bounds__(256) void cvt_wt(const float* __restrict__ w,
                                              short* __restrict__ wtb) {
    __shared__ float T[64][69];
    const int n0 = blockIdx.x * 64, k0 = blockIdx.y * 64;
    const int t = threadIdx.x;
    {
        const int kr = t >> 4, nc = (t & 15) * 4;
        #pragma unroll
        for (int i = 0; i < 4; ++i) {
            float4 v = *(const float4*)(w + (size_t)(k0 + kr + i * 16) * 3072 + n0 + nc);
            T[kr + i * 16][nc + 0] = v.x; T[kr + i * 16][nc + 1] = v.y;
            T[kr + i * 16][nc + 2] = v.z; T[kr + i * 16][nc + 3] = v.w;
        }
    }
    __syncthreads();
    const int nr = t >> 4, kc = (t & 15) * 4;
    #pragma unroll
    for (int i = 0; i < 4; ++i) {
        const int n = n0 + nr + i * 16;
        const float sc = (n >= 1024 && n < 2048) ? (LOG2E / 32.0f) : 1.0f;
        short4 o;
        o.x = f2bf(T[kc + 0][nr + i * 16] * sc);
        o.y = f2bf(T[kc + 1][nr + i * 16] * sc);
        o.z = f2bf(T[kc + 2][nr + i * 16] * sc);
        o.w = f2bf(T[kc + 3][nr + i * 16] * sc);
        *(short4*)(wtb + (size_t)n * 1024 + k0 + kc) = o;
    }
}

// ---- QKV GEMM (m97 structure): 128x128 tile, BK=64, global_load_lds ----
__global__ __launch_bounds__(256) void qkv_gemm(const short* __restrict__ xb,
                                                const short* __restrict__ wtb,
                                                short* __restrict__ kq,
                                                short* __restrict__ vt) {
    __shared__ short As[128 * 64];
    __shared__ short Bs[128 * 64];
    const int col0 = blockIdx.x * 128, row0 = blockIdx.y * 128;
    const int tid = threadIdx.x, w = tid >> 6, lane = tid & 63;
    const int lmod = lane & 15, ldiv = lane >> 4;
    const int wr = (w >> 1) * 64, wc = (w & 1) * 64;

    f32x4 acc[4][4] = {};
    const short* Ag = xb  + (size_t)row0 * DM;
    const short* Bg = wtb + (size_t)col0 * DM;

    for (int k0 = 0; k0 < DM; k0 += 64) {
        __syncthreads();
        #pragma unroll
        for (int t = 0; t < 4; ++t) {
            const int o = (w * 4 + t) * 1024 + lane * 16;
            const int r = o >> 7, cs = (o & 127) >> 1;
            load_lds16(Ag + (size_t)r * DM + k0 + cs, As + (w * 4 + t) * 512);
            load_lds16(Bg + (size_t)r * DM + k0 + cs, Bs + (w * 4 + t) * 512);
        }
        __syncthreads();
        #pragma unroll
        for (int ks = 0; ks < 2; ++ks) {
            bf16x8 af[4], bf[4];
            #pragma unroll
            for (int i = 0; i < 4; ++i)
                af[i] = *(const bf16x8*)(As + (wr + i * 16 + lmod) * 64 + ks * 32 + ldiv * 8);
            #pragma unroll
            for (int j = 0; j < 4; ++j)
                bf[j] = *(const bf16x8*)(Bs + (wc + j * 16 + lmod) * 64 + ks * 32 + ldiv * 8);
            #pragma unroll
            for (int i = 0; i < 4; ++i)
                #pragma unroll
                for (int j = 0; j < 4; ++j)
                    acc[i][j] = __builtin_amdgcn_mfma_f32_16x16x32_bf16(af[i], bf[j], acc[i][j], 0, 0, 0);
        }
    }

    if (col0 < 2048) {
        #pragma unroll
        for (int i = 0; i < 4; ++i)
            #pragma unroll
            for (int j = 0; j < 4; ++j)
                #pragma unroll
                for (int r = 0; r < 4; ++r)
                    kq[(size_t)(row0 + wr + i * 16 + ldiv * 4 + r) * 2048
                       + col0 + wc + j * 16 + lmod] = f2bf(acc[i][j][r]);
    } else {
        #pragma unroll
        for (int i = 0; i < 4; ++i) {
            const int ig = row0 + wr + i * 16 + ldiv * 4;
            #pragma unroll
            for (int j = 0; j < 4; ++j) {
                const int cg = col0 + wc + j * 16 + lmod - 2048;
                const int h = cg >> 6, d = cg & 63;
                bf16x4 p;
                p[0]=f2bf(acc[i][j][0]); p[1]=f2bf(acc[i][j][1]);
                p[2]=f2bf(acc[i][j][2]); p[3]=f2bf(acc[i][j][3]);
                *(bf16x4*)(vt + (size_t)(h * 64 + d) * SEQ + ig) = p;
            }
        }
    }
}

// ---- flash attention, ALiBi + causal, fixed-max exp2-domain softmax ----
// Complementary-qt pairing (uniform 65 tile-units/block) + register-prefetch
// pipeline for K/V staging. Q pre-scaled by log2e/32 (folded into wtb).
__global__ __launch_bounds__(256) void attn(const short* __restrict__ kq,
                                            const short* __restrict__ vt,
                                            float* __restrict__ out) {
    __shared__ short Ks[64 * KPAD];
    __shared__ short Vs[64 * KPAD];
    __shared__ short Ps[4 * 16 * PPAD];

    const int b = blockIdx.x;
    const int pi = b >> 4, h = b & 15;
    const int tid = threadIdx.x, w = tid >> 6, lane = tid & 63;
    const int lmod = lane & 15, ldiv = lane >> 4;
    const float slope2 = exp2f(-0.5f * (float)(h + 1)) * LOG2E;  // slope*log2(e)

    const int srow = tid >> 3;          // staging row 0..31
    const int sch  = (tid & 7) * 8;     // staging 8-short chunk
    const int dji  = lmod - (w * 16 + ldiv * 4);   // (j - i) lane part, within tile
    const float bl = slope2 * (float)dji;

    short* pw = Ps + w * 16 * PPAD;

    for (int side = 0; side < 2; ++side) {
        const int qt = side ? pi : 63 - pi;

        bf16x8 qf[2];
        {
            const int row = qt * 64 + w * 16 + lmod;
            const short* qp = kq + (size_t)row * 2048 + 1024 + h * 64;
            qf[0] = *(const bf16x8*)(qp + ldiv * 8);
            qf[1] = *(const bf16x8*)(qp + 32 + ldiv * 8);
        }
        f32x4 O[4] = {};
        float lsum[4] = {0.f, 0.f, 0.f, 0.f};

        uint4 ka0, ka1, va0, va1, kb0, kb1, vb0, vb1;

        auto sload = [&](int kt, uint4& k0, uint4& k1, uint4& v0, uint4& v1) {
            const short* kb_ = kq + (size_t)(kt * 64 + srow) * 2048 + h * 64 + sch;
            k0 = *(const uint4*)kb_;
            k1 = *(const uint4*)(kb_ + (size_t)32 * 2048);
            const short* vb_ = vt + (size_t)(h * 64 + srow) * SEQ + kt * 64 + sch;
            v0 = *(const uint4*)vb_;
            v1 = *(const uint4*)(vb_ + (size_t)32 * SEQ);
        };
        auto swrite = [&](const uint4& k0, const uint4& k1,
                          const uint4& v0, const uint4& v1) {
            *(uint4*)(Ks + srow * KPAD + sch) = k0;
            *(uint4*)(Ks + (srow + 32) * KPAD + sch) = k1;
            *(uint4*)(Vs + srow * KPAD + sch) = v0;
            *(uint4*)(Vs + (srow + 32) * KPAD + sch) = v1;
        };
        auto compute = [&](int kt, bool diag) {
            f32x4 s[4] = {};
            #pragma unroll
            for (int nt = 0; nt < 4; ++nt)
                #pragma unroll
                for (int ks = 0; ks < 2; ++ks) {
                    bf16x8 kf = *(const bf16x8*)(Ks + (nt * 16 + lmod) * KPAD + ks * 32 + ldiv * 8);
                    s[nt] = __builtin_amdgcn_mfma_f32_16x16x32_bf16(qf[ks], kf, s[nt], 0, 0, 0);
                }
            const float bt = bl + slope2 * 64.0f * (float)(kt - qt);
            #pragma unroll
            for (int nt = 0; nt < 4; ++nt) {
                #pragma unroll
                for (int r = 0; r < 4; ++r) {
                    float v = s[nt][r] + (bt + slope2 * (float)(nt * 16 - r));
                    if (diag && (nt * 16 - r + dji) > 0) v = -1e30f;
                    const float p = __builtin_amdgcn_exp2f(v);
                    lsum[r] += p;
                    pw[(ldiv * 4 + r) * PPAD + nt * 16 + lmod] = f2bf(p);
                }
            }
            // same-wave LDS RAW: no barrier needed (lgkmcnt ordering)
            bf16x8 pa0 = *(const bf16x8*)(pw + lmod * PPAD + ldiv * 8);
            bf16x8 pa1 = *(const bf16x8*)(pw + lmod * PPAD + 32 + ldiv * 8);
            #pragma unroll
            for (int nt = 0; nt < 4; ++nt) {
                bf16x8 vf0 = *(const bf16x8*)(Vs + (nt * 16 + lmod) * KPAD + ldiv * 8);
                bf16x8 vf1 = *(const bf16x8*)(Vs + (nt * 16 + lmod) * KPAD + 32 + ldiv * 8);
                O[nt] = __builtin_amdgcn_mfma_f32_16x16x32_bf16(pa0, vf0, O[nt], 0, 0, 0);
                O[nt] = __builtin_amdgcn_mfma_f32_16x16x32_bf16(pa1, vf1, O[nt], 0, 0, 0);
            }
        };

        sload(0, ka0, ka1, va0, va1);
        int kt = 0;
        while (true) {
            if (kt < qt) sload(kt + 1, kb0, kb1, vb0, vb1);
            __syncthreads();
            swrite(ka0, ka1, va0, va1);
            __syncthreads();
            compute(kt, kt == qt);
            if (++kt > qt) break;
            if (kt < qt) sload(kt + 1, ka0, ka1, va0, va1);
            __syncthreads();
            swrite(kb0, kb1, vb0, vb1);
            __syncthreads();
            compute(kt, kt == qt);
            if (++kt > qt) break;
        }

        #pragma unroll
        for (int r = 0; r < 4; ++r) {
            float v2 = lsum[r];
            v2 += __shfl_xor(v2, 1, 16);
            v2 += __shfl_xor(v2, 2, 16);
            v2 += __shfl_xor(v2, 4, 16);
            v2 += __shfl_xor(v2, 8, 16);
            lsum[r] = 1.0f / v2;
        }
        const int i0 = qt * 64 + w * 16 + ldiv * 4;
        #pragma unroll
        for (int nt = 0; nt < 4; ++nt)
            #pragma unroll
            for (int r = 0; r < 4; ++r)
                out[(size_t)(i0 + r) * DM + h * 64 + nt * 16 + lmod] = O[nt][r] * lsum[r];
    }
}

extern "C" void kernel_launch(void* const* d_in, const int* in_sizes, int n_in,
                              void* d_out, int out_size, void* d_ws, size_t ws_size,
                              hipStream_t stream) {
    const float* x = (const float*)d_in[0];   // [1,4096,1024] fp32
    const float* w = (const float*)d_in[1];   // [1024,3072] fp32
    float* out = (float*)d_out;

    char* ws = (char*)d_ws;
    short* xb  = (short*)(ws);                        //  8 MB: x bf16
    short* wtb = (short*)(ws + ((size_t)8  << 20));   //  6 MB: w^T bf16 (Q-scaled)
    short* kq  = (short*)(ws + ((size_t)14 << 20));   // 16 MB: K|Q [4096][2048]
    short* vt  = (short*)(ws + ((size_t)30 << 20));   //  8 MB: V^T [16][64][4096]

    cvt_x  <<<SEQ * DM / (256 * 8), 256, 0, stream>>>(x, xb);
    cvt_wt <<<dim3(3072 / 64, 1024 / 64), 256, 0, stream>>>(w, wtb);
    qkv_gemm<<<dim3(3072 / 128, SEQ / 128), 256, 0, stream>>>(xb, wtb, kq, vt);
    attn   <<<32 * NH, 256, 0, stream>>>(kq, vt, out);
}